// Round 1
// baseline (89.232 us; speedup 1.0000x reference)
//
#include <hip/hip_runtime.h>
#include <hip/hip_bf16.h>
#include <hip/hip_fp16.h>

#define BB 8
#define NN 1024
#define FIN 128
#define FOUT 64
#define HH 4
#define EPSV 1e-7f
#define SLOPE 0.2f
#define LOG2E 1.44269504088896340736f

typedef _Float16 v8h __attribute__((ext_vector_type(8)));
typedef float v4f __attribute__((ext_vector_type(4)));

// ---------------- K0: Wt[c][k] = (f16) W[h][k][o], c = h*64+o ----------------
__global__ __launch_bounds__(256) void k0_wt(const float* __restrict__ W,
                                             _Float16* __restrict__ Wt) {
  for (int it = 0; it < 4; ++it) {
    int idx = blockIdx.x * 1024 + it * 256 + threadIdx.x;  // 32 blocks * 1024 = 32768
    int c = idx >> 7, k = idx & 127;
    Wt[idx] = (_Float16)W[(size_t)(c >> 6) * 8192 + k * 64 + (c & 63)];
  }
}

// ---------------- K1: Wh = x @ W via MFMA f16, store WhH[(b*H+h)*N+n][o] ----
// grid 512 (M-tiles of 16 rows over B*N=8192), block 256 = 4 waves (wave = head)
__global__ __launch_bounds__(256) void k1_whm(const float* __restrict__ x,
                                              const _Float16* __restrict__ Wt,
                                              _Float16* __restrict__ WhH) {
  int tid = threadIdx.x;
  int w = tid >> 6, l = tid & 63;
  int kg = l >> 4, ln = l & 15;
  int gr_a = blockIdx.x * 16 + ln;  // global row for A-frag loads
  const float* xp = x + (size_t)gr_a * FIN + kg * 8;
  v4f acc[4] = {{}, {}, {}, {}};
#pragma unroll
  for (int ks = 0; ks < 4; ++ks) {
    int k = ks * 32;
    float4 x0 = *(const float4*)(xp + k);
    float4 x1 = *(const float4*)(xp + k + 4);
    v8h af;
    af[0] = (_Float16)x0.x; af[1] = (_Float16)x0.y;
    af[2] = (_Float16)x0.z; af[3] = (_Float16)x0.w;
    af[4] = (_Float16)x1.x; af[5] = (_Float16)x1.y;
    af[6] = (_Float16)x1.z; af[7] = (_Float16)x1.w;
#pragma unroll
    for (int t = 0; t < 4; ++t) {
      int c = w * 64 + t * 16 + ln;
      v8h bf = *(const v8h*)(Wt + (size_t)c * FIN + k + kg * 8);
      acc[t] = __builtin_amdgcn_mfma_f32_16x16x32_f16(af, bf, acc[t], 0, 0, 0);
    }
  }
  // D layout: row(local M) = kg*4 + r, col(local N) = l&15 (per verified C/D map)
#pragma unroll
  for (int t = 0; t < 4; ++t) {
#pragma unroll
    for (int r = 0; r < 4; ++r) {
      int gr = blockIdx.x * 16 + kg * 4 + r;
      int b_ = gr >> 10, n_ = gr & 1023;
      WhH[(((size_t)b_ * HH + w) * NN + n_) * 64 + (t * 16 + ln)] =
          (_Float16)acc[t][r];
    }
  }
}

// ---------------- K1b: si2 = (Wh·a1)*log2e ; tj2 = (Wh·a2 + ab)*log2e -------
// grid 8192 (4 rows per block, one row per wave), block 256
__global__ __launch_bounds__(256) void k1b_s(const _Float16* __restrict__ WhH,
                                             const float* __restrict__ aw,
                                             const float* __restrict__ ab,
                                             float* __restrict__ si2,
                                             float* __restrict__ tj2) {
  int w = threadIdx.x >> 6, o = threadIdx.x & 63;
  int row = blockIdx.x * 4 + w;       // row = (b*H+h)*N + n
  int h = (row >> 10) & 3;
  float val = (float)WhH[(size_t)row * 64 + o];
  float v1 = val * aw[h * 128 + o];
  float v2 = val * aw[h * 128 + 64 + o];
#pragma unroll
  for (int off = 32; off; off >>= 1) {
    v1 += __shfl_xor(v1, off);
    v2 += __shfl_xor(v2, off);
  }
  if (o == 0) {
    si2[row] = v1 * LOG2E;
    tj2[row] = (v2 + ab[h]) * LOG2E;
  }
}

// ---------------- K2: partial column sums of exps over i ---------------------
// grid (4 j-tiles, 8 i-splits, B), block 256 (one j per thread, all 4 heads)
__global__ __launch_bounds__(256) void k2_colsum(const float* __restrict__ A,
                                                 const float* __restrict__ si2,
                                                 const float* __restrict__ tj2,
                                                 float* __restrict__ part) {
  __shared__ float sil[4][128];
  int b = blockIdx.z, is = blockIdx.y, jt = blockIdx.x;
  int tid = threadIdx.x;
  int j = jt * 256 + tid;
  int i0 = is * 128;
  for (int t = tid; t < 512; t += 256) {
    int h = t >> 7, ii = t & 127;
    sil[h][ii] = si2[((size_t)(b * HH + h)) * NN + i0 + ii];
  }
  __syncthreads();
  float tjv[4], acc[4] = {0.f, 0.f, 0.f, 0.f};
#pragma unroll
  for (int h = 0; h < 4; ++h) tjv[h] = tj2[((size_t)(b * HH + h)) * NN + j];
  const float* Ap = A + ((size_t)b * NN + i0) * NN + j;
  for (int ii = 0; ii < 128; ++ii) {
    float a = Ap[(size_t)ii * NN];
#pragma unroll
    for (int h = 0; h < 4; ++h) {
      float f = sil[h][ii] + tjv[h];
      float g = fmaxf(f, SLOPE * f);
      acc[h] += a * __builtin_amdgcn_exp2f(g);
    }
  }
#pragma unroll
  for (int h = 0; h < 4; ++h)
    part[((size_t)(is * 32) + b * HH + h) * NN + j] = acc[h];
}

// ---------------- K3: r[j] = 1/(colsum+eps); VT[bh][o][j] = (f16) r*Wh ------
// grid (16 j-tiles, B*H), block 256
__global__ __launch_bounds__(256) void k3_scale_tr(
    const _Float16* __restrict__ WhH, const float* __restrict__ part,
    _Float16* __restrict__ VT) {
  __shared__ float rbuf[64];
  __shared__ _Float16 tile[64 * 66];
  int bh = blockIdx.y, j0 = blockIdx.x * 64;
  int tid = threadIdx.x;
  if (tid < 64) {
    float s = 0.f;
#pragma unroll
    for (int is = 0; is < 8; ++is)
      s += part[((size_t)(is * 32) + bh) * NN + j0 + tid];
    rbuf[tid] = 1.0f / (s + EPSV);
  }
  __syncthreads();
#pragma unroll
  for (int it = 0; it < 16; ++it) {
    int lin = it * 256 + tid;
    int jj = lin >> 6, o = lin & 63;
    float v = (float)WhH[((size_t)bh * NN + j0 + jj) * 64 + o] * rbuf[jj];
    tile[o * 66 + jj] = (_Float16)v;
  }
  __syncthreads();
#pragma unroll
  for (int it = 0; it < 16; ++it) {
    int lin = it * 256 + tid;
    int o = lin >> 6, jj = lin & 63;
    VT[((size_t)bh * 64 + o) * NN + j0 + jj] = tile[o * 66 + jj];
  }
}

// ---------------- K4: out[i,:] = sum_j P[i,j] * V'[j,:] via MFMA ------------
// P computed directly in A-fragment layout. grid (16 i-tiles, H, B), 4 waves.
__global__ __launch_bounds__(256) void k4_pv(const float* __restrict__ A,
                                             const float* __restrict__ si2,
                                             const float* __restrict__ tj2,
                                             const _Float16* __restrict__ VT,
                                             float* __restrict__ out) {
  __shared__ float tjl[1024];
  __shared__ float sil[64];
  int b = blockIdx.z, h = blockIdx.y, it = blockIdx.x;
  int bh = b * HH + h;
  int i0 = it * 64;
  int tid = threadIdx.x;
  for (int t = tid; t < 1024; t += 256) tjl[t] = tj2[(size_t)bh * NN + t];
  if (tid < 64) sil[tid] = si2[(size_t)bh * NN + i0 + tid];
  __syncthreads();
  int w = tid >> 6, l = tid & 63;
  int kg = l >> 4, ln = l & 15;
  int il = w * 16 + ln;
  float si = sil[il];
  v4f acc0 = {}, acc1 = {}, acc2 = {}, acc3 = {};
  const float* Arow = A + ((size_t)b * NN + i0 + il) * NN;
  const _Float16* VTb = VT + (size_t)bh * 64 * NN;

#define PEXP(av, tv) \
  ((av) * __builtin_amdgcn_exp2f(fmaxf(si + (tv), SLOPE * (si + (tv)))))

  for (int jb = 0; jb < NN; jb += 32) {
    int j = jb + kg * 8;
    float4 a0 = *(const float4*)(Arow + j);
    float4 a1 = *(const float4*)(Arow + j + 4);
    float4 t0 = *(const float4*)(tjl + j);
    float4 t1 = *(const float4*)(tjl + j + 4);
    v8h af;
    af[0] = (_Float16)PEXP(a0.x, t0.x);
    af[1] = (_Float16)PEXP(a0.y, t0.y);
    af[2] = (_Float16)PEXP(a0.z, t0.z);
    af[3] = (_Float16)PEXP(a0.w, t0.w);
    af[4] = (_Float16)PEXP(a1.x, t1.x);
    af[5] = (_Float16)PEXP(a1.y, t1.y);
    af[6] = (_Float16)PEXP(a1.z, t1.z);
    af[7] = (_Float16)PEXP(a1.w, t1.w);
    v8h b0 = *(const v8h*)(VTb + (size_t)(0 * 16 + ln) * NN + j);
    v8h b1 = *(const v8h*)(VTb + (size_t)(1 * 16 + ln) * NN + j);
    v8h b2 = *(const v8h*)(VTb + (size_t)(2 * 16 + ln) * NN + j);
    v8h b3 = *(const v8h*)(VTb + (size_t)(3 * 16 + ln) * NN + j);
    acc0 = __builtin_amdgcn_mfma_f32_16x16x32_f16(af, b0, acc0, 0, 0, 0);
    acc1 = __builtin_amdgcn_mfma_f32_16x16x32_f16(af, b1, acc1, 0, 0, 0);
    acc2 = __builtin_amdgcn_mfma_f32_16x16x32_f16(af, b2, acc2, 0, 0, 0);
    acc3 = __builtin_amdgcn_mfma_f32_16x16x32_f16(af, b3, acc3, 0, 0, 0);
  }
#undef PEXP

  // D layout: col = ln, row = kg*4 + r. out[b][i][h*64+o]
#pragma unroll
  for (int r = 0; r < 4; ++r) {
    int gi = i0 + w * 16 + kg * 4 + r;
    float* op = out + ((size_t)b * NN + gi) * 256 + h * 64;
    op[0 * 16 + ln] = acc0[r];
    op[1 * 16 + ln] = acc1[r];
    op[2 * 16 + ln] = acc2[r];
    op[3 * 16 + ln] = acc3[r];
  }
}

extern "C" void kernel_launch(void* const* d_in, const int* in_sizes, int n_in,
                              void* d_out, int out_size, void* d_ws,
                              size_t ws_size, hipStream_t stream) {
  const float* A = (const float*)d_in[0];
  const float* x = (const float*)d_in[1];
  const float* W = (const float*)d_in[2];
  const float* aw = (const float*)d_in[3];
  const float* ab = (const float*)d_in[4];
  float* out = (float*)d_out;
  char* ws = (char*)d_ws;
  // workspace layout (9.25 MB total)
  _Float16* WhH = (_Float16*)ws;                       // 4 MB: (B,H,N,64) f16
  _Float16* VT = (_Float16*)(ws + (4u << 20));         // 4 MB: (B,H,64,N) f16
  _Float16* Wt = (_Float16*)(ws + (8u << 20));         // 64 KB: (256,128) f16
  float* si2 = (float*)(ws + (8u << 20) + (256u << 10));   // 128 KB
  float* tj2 = (float*)(ws + (8u << 20) + (384u << 10));   // 128 KB
  float* part = (float*)(ws + (8u << 20) + (512u << 10));  // 1 MB

  hipLaunchKernelGGL(k0_wt, dim3(32), dim3(256), 0, stream, W, Wt);
  hipLaunchKernelGGL(k1_whm, dim3(512), dim3(256), 0, stream, x, Wt, WhH);
  hipLaunchKernelGGL(k1b_s, dim3(8192), dim3(256), 0, stream, WhH, aw, ab, si2,
                     tj2);
  hipLaunchKernelGGL(k2_colsum, dim3(4, 8, BB), dim3(256), 0, stream, A, si2,
                     tj2, part);
  hipLaunchKernelGGL(k3_scale_tr, dim3(16, BB * HH), dim3(256), 0, stream, WhH,
                     part, VT);
  hipLaunchKernelGGL(k4_pv, dim3(16, HH, BB), dim3(256), 0, stream, A, si2,
                     tj2, VT, out);
}

// Round 2
// 77.903 us; speedup vs baseline: 1.1454x; 1.1454x over previous
//
#include <hip/hip_runtime.h>
#include <hip/hip_bf16.h>
#include <hip/hip_fp16.h>

#define BB 8
#define NN 1024
#define FIN 128
#define FOUT 64
#define HH 4
#define EPSV 1e-7f
#define SLOPE 0.2f
#define LOG2E 1.44269504088896340736f

typedef _Float16 v8h __attribute__((ext_vector_type(8)));
typedef float v4f __attribute__((ext_vector_type(4)));

// ---------------- K0: Wt[c][k] = (f16) W[h][k][o], c = h*64+o ----------------
__global__ __launch_bounds__(256) void k0_wt(const float* __restrict__ W,
                                             _Float16* __restrict__ Wt) {
  for (int it = 0; it < 4; ++it) {
    int idx = blockIdx.x * 1024 + it * 256 + threadIdx.x;
    int c = idx >> 7, k = idx & 127;
    Wt[idx] = (_Float16)W[(size_t)(c >> 6) * 8192 + k * 64 + (c & 63)];
  }
}

// ---------------- K1: Wh = x @ W via MFMA f16 + fused s_i/s_j ---------------
// grid 512 (M-tiles of 16 rows over B*N=8192), block 256 = 4 waves (wave = head)
__global__ __launch_bounds__(256) void k1_whm(const float* __restrict__ x,
                                              const _Float16* __restrict__ Wt,
                                              const float* __restrict__ aw,
                                              const float* __restrict__ ab,
                                              _Float16* __restrict__ WhH,
                                              float* __restrict__ si2,
                                              float* __restrict__ tj2) {
  int tid = threadIdx.x;
  int w = tid >> 6, l = tid & 63;
  int kg = l >> 4, ln = l & 15;
  int gr_a = blockIdx.x * 16 + ln;  // global row for A-frag loads
  const float* xp = x + (size_t)gr_a * FIN + kg * 8;
  v4f acc[4] = {{}, {}, {}, {}};
#pragma unroll
  for (int ks = 0; ks < 4; ++ks) {
    int k = ks * 32;
    float4 x0 = *(const float4*)(xp + k);
    float4 x1 = *(const float4*)(xp + k + 4);
    v8h af;
    af[0] = (_Float16)x0.x; af[1] = (_Float16)x0.y;
    af[2] = (_Float16)x0.z; af[3] = (_Float16)x0.w;
    af[4] = (_Float16)x1.x; af[5] = (_Float16)x1.y;
    af[6] = (_Float16)x1.z; af[7] = (_Float16)x1.w;
#pragma unroll
    for (int t = 0; t < 4; ++t) {
      int c = w * 64 + t * 16 + ln;
      v8h bf = *(const v8h*)(Wt + (size_t)c * FIN + k + kg * 8);
      acc[t] = __builtin_amdgcn_mfma_f32_16x16x32_f16(af, bf, acc[t], 0, 0, 0);
    }
  }
  // fused s_i / s_j from f32 accumulators
  float a1v[4], a2v[4];
#pragma unroll
  for (int t = 0; t < 4; ++t) {
    a1v[t] = aw[w * 128 + t * 16 + ln];
    a2v[t] = aw[w * 128 + 64 + t * 16 + ln];
  }
  float abv = ab[w];
#pragma unroll
  for (int r = 0; r < 4; ++r) {
    float v1 = acc[0][r] * a1v[0] + acc[1][r] * a1v[1] +
               acc[2][r] * a1v[2] + acc[3][r] * a1v[3];
    float v2 = acc[0][r] * a2v[0] + acc[1][r] * a2v[1] +
               acc[2][r] * a2v[2] + acc[3][r] * a2v[3];
#pragma unroll
    for (int off = 1; off < 16; off <<= 1) {
      v1 += __shfl_xor(v1, off);
      v2 += __shfl_xor(v2, off);
    }
    if (ln == 0) {
      int gr = blockIdx.x * 16 + kg * 4 + r;
      int b_ = gr >> 10, n_ = gr & 1023;
      size_t row = ((size_t)b_ * HH + w) * NN + n_;
      si2[row] = v1 * LOG2E;
      tj2[row] = (v2 + abv) * LOG2E;
    }
  }
  // store Wh (f16)
#pragma unroll
  for (int t = 0; t < 4; ++t) {
#pragma unroll
    for (int r = 0; r < 4; ++r) {
      int gr = blockIdx.x * 16 + kg * 4 + r;
      int b_ = gr >> 10, n_ = gr & 1023;
      WhH[(((size_t)b_ * HH + w) * NN + n_) * 64 + (t * 16 + ln)] =
          (_Float16)acc[t][r];
    }
  }
}

// ---------------- K2: partial column sums of exps over i ---------------------
// grid (4 j-tiles, 32 i-splits, B), block 256 (one j per thread, all 4 heads)
__global__ __launch_bounds__(256) void k2_colsum(const float* __restrict__ A,
                                                 const float* __restrict__ si2,
                                                 const float* __restrict__ tj2,
                                                 float* __restrict__ part) {
  __shared__ float sil[4][32];
  int b = blockIdx.z, is = blockIdx.y, jt = blockIdx.x;
  int tid = threadIdx.x;
  int j = jt * 256 + tid;
  int i0 = is * 32;
  if (tid < 128) {
    int h = tid >> 5, ii = tid & 31;
    sil[h][ii] = si2[((size_t)(b * HH + h)) * NN + i0 + ii];
  }
  __syncthreads();
  float tjv[4], acc[4] = {0.f, 0.f, 0.f, 0.f};
#pragma unroll
  for (int h = 0; h < 4; ++h) tjv[h] = tj2[((size_t)(b * HH + h)) * NN + j];
  const float* Ap = A + ((size_t)b * NN + i0) * NN + j;
#pragma unroll 4
  for (int ii = 0; ii < 32; ++ii) {
    float a = Ap[(size_t)ii * NN];
#pragma unroll
    for (int h = 0; h < 4; ++h) {
      float f = sil[h][ii] + tjv[h];
      float g = fmaxf(f, SLOPE * f);
      acc[h] += a * __builtin_amdgcn_exp2f(g);
    }
  }
#pragma unroll
  for (int h = 0; h < 4; ++h)
    part[((size_t)(is * 32) + b * HH + h) * NN + j] = acc[h];
}

// ---------------- K3: r[j] = 1/(colsum+eps); VT[bh][o][j] = (f16) r*Wh ------
// grid (16 j-tiles, B*H), block 256
__global__ __launch_bounds__(256) void k3_scale_tr(
    const _Float16* __restrict__ WhH, const float* __restrict__ part,
    _Float16* __restrict__ VT) {
  __shared__ float rbuf[64];
  __shared__ _Float16 tile[64 * 66];
  int bh = blockIdx.y, j0 = blockIdx.x * 64;
  int tid = threadIdx.x;
  if (tid < 64) {
    float s = 0.f;
#pragma unroll
    for (int is = 0; is < 32; ++is)
      s += part[((size_t)(is * 32) + bh) * NN + j0 + tid];
    rbuf[tid] = 1.0f / (s + EPSV);
  }
  __syncthreads();
#pragma unroll
  for (int it = 0; it < 16; ++it) {
    int lin = it * 256 + tid;
    int jj = lin >> 6, o = lin & 63;
    float v = (float)WhH[((size_t)bh * NN + j0 + jj) * 64 + o] * rbuf[jj];
    tile[o * 66 + jj] = (_Float16)v;
  }
  __syncthreads();
#pragma unroll
  for (int it = 0; it < 16; ++it) {
    int lin = it * 256 + tid;
    int o = lin >> 6, jj = lin & 63;
    VT[((size_t)bh * 64 + o) * NN + j0 + jj] = tile[o * 66 + jj];
  }
}

// ---------------- K4: out[i,:] = sum_j P[i,j] * V'[j,:] via MFMA ------------
// 16-row i-tile per block; 4 waves each own a 256-wide j-quarter; LDS reduce.
// grid (64 i-tiles, H, B), block 256.
__global__ __launch_bounds__(256) void k4_pv(const float* __restrict__ A,
                                             const float* __restrict__ si2,
                                             const float* __restrict__ tj2,
                                             const _Float16* __restrict__ VT,
                                             float* __restrict__ out) {
  __shared__ float tjl[1024];
  __shared__ float sil[16];
  __shared__ float red[3][64][17];
  int b = blockIdx.z, h = blockIdx.y, it = blockIdx.x;
  int bh = b * HH + h;
  int i0 = it * 16;
  int tid = threadIdx.x;
  for (int t = tid; t < 1024; t += 256) tjl[t] = tj2[(size_t)bh * NN + t];
  if (tid < 16) sil[tid] = si2[(size_t)bh * NN + i0 + tid];
  __syncthreads();
  int w = tid >> 6, l = tid & 63;
  int kg = l >> 4, ln = l & 15;
  float si = sil[ln];
  v4f acc[4] = {{}, {}, {}, {}};
  const float* Arow = A + ((size_t)b * NN + i0 + ln) * NN;
  const _Float16* VTb = VT + (size_t)bh * 64 * NN;
  int jbase = w * 256;

#define PEXP(av, tv) \
  ((av) * __builtin_amdgcn_exp2f(fmaxf(si + (tv), SLOPE * (si + (tv)))))

#pragma unroll 2
  for (int jb = 0; jb < 256; jb += 32) {
    int j = jbase + jb + kg * 8;
    float4 a0 = *(const float4*)(Arow + j);
    float4 a1 = *(const float4*)(Arow + j + 4);
    float4 t0 = *(const float4*)(tjl + j);
    float4 t1 = *(const float4*)(tjl + j + 4);
    v8h af;
    af[0] = (_Float16)PEXP(a0.x, t0.x);
    af[1] = (_Float16)PEXP(a0.y, t0.y);
    af[2] = (_Float16)PEXP(a0.z, t0.z);
    af[3] = (_Float16)PEXP(a0.w, t0.w);
    af[4] = (_Float16)PEXP(a1.x, t1.x);
    af[5] = (_Float16)PEXP(a1.y, t1.y);
    af[6] = (_Float16)PEXP(a1.z, t1.z);
    af[7] = (_Float16)PEXP(a1.w, t1.w);
    v8h b0 = *(const v8h*)(VTb + (size_t)(0 * 16 + ln) * NN + j);
    v8h b1 = *(const v8h*)(VTb + (size_t)(1 * 16 + ln) * NN + j);
    v8h b2 = *(const v8h*)(VTb + (size_t)(2 * 16 + ln) * NN + j);
    v8h b3 = *(const v8h*)(VTb + (size_t)(3 * 16 + ln) * NN + j);
    acc[0] = __builtin_amdgcn_mfma_f32_16x16x32_f16(af, b0, acc[0], 0, 0, 0);
    acc[1] = __builtin_amdgcn_mfma_f32_16x16x32_f16(af, b1, acc[1], 0, 0, 0);
    acc[2] = __builtin_amdgcn_mfma_f32_16x16x32_f16(af, b2, acc[2], 0, 0, 0);
    acc[3] = __builtin_amdgcn_mfma_f32_16x16x32_f16(af, b3, acc[3], 0, 0, 0);
  }
#undef PEXP

  // cross-wave reduction: waves 1..3 dump accs, wave 0 combines + stores
  if (w) {
#pragma unroll
    for (int t = 0; t < 4; ++t)
#pragma unroll
      for (int r = 0; r < 4; ++r) red[w - 1][l][t * 4 + r] = acc[t][r];
  }
  __syncthreads();
  if (w == 0) {
#pragma unroll
    for (int q = 0; q < 3; ++q)
#pragma unroll
      for (int t = 0; t < 4; ++t)
#pragma unroll
        for (int r = 0; r < 4; ++r) acc[t][r] += red[q][l][t * 4 + r];
    // D layout: col = ln, row = kg*4 + r. out[b][i][h*64+o]
#pragma unroll
    for (int r = 0; r < 4; ++r) {
      int gi = i0 + kg * 4 + r;
      float* op = out + ((size_t)b * NN + gi) * 256 + h * 64;
      op[0 * 16 + ln] = acc[0][r];
      op[1 * 16 + ln] = acc[1][r];
      op[2 * 16 + ln] = acc[2][r];
      op[3 * 16 + ln] = acc[3][r];
    }
  }
}

extern "C" void kernel_launch(void* const* d_in, const int* in_sizes, int n_in,
                              void* d_out, int out_size, void* d_ws,
                              size_t ws_size, hipStream_t stream) {
  const float* A = (const float*)d_in[0];
  const float* x = (const float*)d_in[1];
  const float* W = (const float*)d_in[2];
  const float* aw = (const float*)d_in[3];
  const float* ab = (const float*)d_in[4];
  float* out = (float*)d_out;
  char* ws = (char*)d_ws;
  // workspace layout (~12.3 MB total)
  _Float16* WhH = (_Float16*)ws;                       // 4 MB: (B,H,N,64) f16
  _Float16* VT = (_Float16*)(ws + (4u << 20));         // 4 MB: (B,H,64,N) f16
  _Float16* Wt = (_Float16*)(ws + (8u << 20));         // 64 KB: (256,128) f16
  float* si2 = (float*)(ws + (8u << 20) + (256u << 10));   // 128 KB
  float* tj2 = (float*)(ws + (8u << 20) + (384u << 10));   // 128 KB
  float* part = (float*)(ws + (8u << 20) + (512u << 10));  // 4 MB (32 splits)

  hipLaunchKernelGGL(k0_wt, dim3(32), dim3(256), 0, stream, W, Wt);
  hipLaunchKernelGGL(k1_whm, dim3(512), dim3(256), 0, stream, x, Wt, aw, ab,
                     WhH, si2, tj2);
  hipLaunchKernelGGL(k2_colsum, dim3(4, 32, BB), dim3(256), 0, stream, A, si2,
                     tj2, part);
  hipLaunchKernelGGL(k3_scale_tr, dim3(16, BB * HH), dim3(256), 0, stream, WhH,
                     part, VT);
  hipLaunchKernelGGL(k4_pv, dim3(64, HH, BB), dim3(256), 0, stream, A, si2,
                     tj2, VT, out);
}

// Round 3
// 54.661 us; speedup vs baseline: 1.6325x; 1.4252x over previous
//
#include <hip/hip_runtime.h>
#include <hip/hip_bf16.h>
#include <hip/hip_fp16.h>

#define BB 8
#define NN 1024
#define FIN 128
#define FOUT 64
#define HH 4
#define EPSV 1e-7f
#define SLOPE 0.2f
#define LOG2E 1.44269504088896340736f

typedef _Float16 v8h __attribute__((ext_vector_type(8)));
typedef _Float16 v4h __attribute__((ext_vector_type(4)));
typedef float v4f __attribute__((ext_vector_type(4)));

// ---------------- K0: Wt[c][k] = (f16) W[h][k][o], c = h*64+o ----------------
__global__ __launch_bounds__(256) void k0_wt(const float* __restrict__ W,
                                             _Float16* __restrict__ Wt) {
  for (int it = 0; it < 4; ++it) {
    int idx = blockIdx.x * 1024 + it * 256 + threadIdx.x;
    int c = idx >> 7, k = idx & 127;
    Wt[idx] = (_Float16)W[(size_t)(c >> 6) * 8192 + k * 64 + (c & 63)];
  }
}

// ---------------- K1: Wh = x @ W via MFMA f16 + fused s_i/s_j ---------------
__global__ __launch_bounds__(256) void k1_whm(const float* __restrict__ x,
                                              const _Float16* __restrict__ Wt,
                                              const float* __restrict__ aw,
                                              const float* __restrict__ ab,
                                              _Float16* __restrict__ WhH,
                                              float* __restrict__ si2,
                                              float* __restrict__ tj2) {
  int tid = threadIdx.x;
  int w = tid >> 6, l = tid & 63;
  int kg = l >> 4, ln = l & 15;
  int gr_a = blockIdx.x * 16 + ln;
  const float* xp = x + (size_t)gr_a * FIN + kg * 8;
  v4f acc[4] = {{}, {}, {}, {}};
#pragma unroll
  for (int ks = 0; ks < 4; ++ks) {
    int k = ks * 32;
    float4 x0 = *(const float4*)(xp + k);
    float4 x1 = *(const float4*)(xp + k + 4);
    v8h af;
    af[0] = (_Float16)x0.x; af[1] = (_Float16)x0.y;
    af[2] = (_Float16)x0.z; af[3] = (_Float16)x0.w;
    af[4] = (_Float16)x1.x; af[5] = (_Float16)x1.y;
    af[6] = (_Float16)x1.z; af[7] = (_Float16)x1.w;
#pragma unroll
    for (int t = 0; t < 4; ++t) {
      int c = w * 64 + t * 16 + ln;
      v8h bf = *(const v8h*)(Wt + (size_t)c * FIN + k + kg * 8);
      acc[t] = __builtin_amdgcn_mfma_f32_16x16x32_f16(af, bf, acc[t], 0, 0, 0);
    }
  }
  float a1v[4], a2v[4];
#pragma unroll
  for (int t = 0; t < 4; ++t) {
    a1v[t] = aw[w * 128 + t * 16 + ln];
    a2v[t] = aw[w * 128 + 64 + t * 16 + ln];
  }
  float abv = ab[w];
#pragma unroll
  for (int r = 0; r < 4; ++r) {
    float v1 = acc[0][r] * a1v[0] + acc[1][r] * a1v[1] +
               acc[2][r] * a1v[2] + acc[3][r] * a1v[3];
    float v2 = acc[0][r] * a2v[0] + acc[1][r] * a2v[1] +
               acc[2][r] * a2v[2] + acc[3][r] * a2v[3];
#pragma unroll
    for (int off = 1; off < 16; off <<= 1) {
      v1 += __shfl_xor(v1, off);
      v2 += __shfl_xor(v2, off);
    }
    if (ln == 0) {
      int gr = blockIdx.x * 16 + kg * 4 + r;
      int b_ = gr >> 10, n_ = gr & 1023;
      size_t row = ((size_t)b_ * HH + w) * NN + n_;
      si2[row] = v1 * LOG2E;
      tj2[row] = (v2 + abv) * LOG2E;
    }
  }
#pragma unroll
  for (int t = 0; t < 4; ++t) {
#pragma unroll
    for (int r = 0; r < 4; ++r) {
      int gr = blockIdx.x * 16 + kg * 4 + r;
      int b_ = gr >> 10, n_ = gr & 1023;
      WhH[(((size_t)b_ * HH + w) * NN + n_) * 64 + (t * 16 + ln)] =
          (_Float16)acc[t][r];
    }
  }
}

// ---------------- K2: partial column sums of exps over i ---------------------
__global__ __launch_bounds__(256) void k2_colsum(const float* __restrict__ A,
                                                 const float* __restrict__ si2,
                                                 const float* __restrict__ tj2,
                                                 float* __restrict__ part) {
  __shared__ float sil[4][32];
  int b = blockIdx.z, is = blockIdx.y, jt = blockIdx.x;
  int tid = threadIdx.x;
  int j = jt * 256 + tid;
  int i0 = is * 32;
  if (tid < 128) {
    int h = tid >> 5, ii = tid & 31;
    sil[h][ii] = si2[((size_t)(b * HH + h)) * NN + i0 + ii];
  }
  __syncthreads();
  float tjv[4], acc[4] = {0.f, 0.f, 0.f, 0.f};
#pragma unroll
  for (int h = 0; h < 4; ++h) tjv[h] = tj2[((size_t)(b * HH + h)) * NN + j];
  const float* Ap = A + ((size_t)b * NN + i0) * NN + j;
#pragma unroll 4
  for (int ii = 0; ii < 32; ++ii) {
    float a = Ap[(size_t)ii * NN];
#pragma unroll
    for (int h = 0; h < 4; ++h) {
      float f = sil[h][ii] + tjv[h];
      float g = fmaxf(f, SLOPE * f);
      acc[h] += a * __builtin_amdgcn_exp2f(g);
    }
  }
#pragma unroll
  for (int h = 0; h < 4; ++h)
    part[((size_t)(is * 32) + b * HH + h) * NN + j] = acc[h];
}

// ---------------- K3: r[j]=1/(colsum+eps); VTt[bh][jb][o][jj] = (f16) r*Wh --
// grid (16 j-tiles of 64, B*H), block 256
__global__ __launch_bounds__(256) void k3_scale_tr(
    const _Float16* __restrict__ WhH, const float* __restrict__ part,
    _Float16* __restrict__ VTt) {
  __shared__ float rbuf[64];
  __shared__ _Float16 tile[64 * 66];
  int bh = blockIdx.y, j0 = blockIdx.x * 64;
  int tid = threadIdx.x;
  if (tid < 64) {
    float s = 0.f;
#pragma unroll
    for (int is = 0; is < 32; ++is)
      s += part[((size_t)(is * 32) + bh) * NN + j0 + tid];
    rbuf[tid] = 1.0f / (s + EPSV);
  }
  __syncthreads();
#pragma unroll
  for (int it = 0; it < 16; ++it) {
    int lin = it * 256 + tid;
    int jj = lin >> 6, o = lin & 63;
    float v = (float)WhH[((size_t)bh * NN + j0 + jj) * 64 + o] * rbuf[jj];
    tile[o * 66 + jj] = (_Float16)v;
  }
  __syncthreads();
  // tiled write: VTt[((bh*32 + jb)*64 + o)*32 + jj]
#pragma unroll
  for (int it = 0; it < 16; ++it) {
    int lin = it * 256 + tid;
    int o = lin >> 6, jj64 = lin & 63;
    int j = j0 + jj64;
    int jb = j >> 5, jj = j & 31;
    VTt[(((size_t)bh * 32 + jb) * 64 + o) * 32 + jj] = tile[o * 66 + jj64];
  }
}

// ---------------- K4: out[i,:] = sum_j P[i,j] * V'[j,:] via MFMA ------------
// Block: 16 i-rows x ALL 4 heads (wave = head). A-tile f16 in LDS (coalesced
// stage), VT in tiled layout -> all global loads coalesced. grid (64, B).
__global__ __launch_bounds__(256) void k4_pv(const float* __restrict__ A,
                                             const float* __restrict__ si2,
                                             const float* __restrict__ tj2,
                                             const _Float16* __restrict__ VTt,
                                             float* __restrict__ out) {
  __shared__ _Float16 Ah[16][1032];  // +8 pad: minimal bank aliasing on b128
  __shared__ float tjl[4][1024];
  __shared__ float sil[4][16];
  int b = blockIdx.y, it = blockIdx.x;
  int i0 = it * 16;
  int tid = threadIdx.x;
  // stage tj (all heads) + si
#pragma unroll
  for (int t2 = 0; t2 < 16; ++t2) {
    int idx = t2 * 256 + tid;
    int h = idx >> 10, j = idx & 1023;
    tjl[h][j] = tj2[((size_t)(b * HH + h)) * NN + j];
  }
  if (tid < 64) {
    int h = tid >> 4, ii = tid & 15;
    sil[h][ii] = si2[((size_t)(b * HH + h)) * NN + i0 + ii];
  }
  // stage A tile -> f16 LDS, fully coalesced (A entries are exactly 0/1)
  const float* Ab = A + ((size_t)b * NN + i0) * NN;
#pragma unroll
  for (int t2 = 0; t2 < 16; ++t2) {
    int idx = t2 * 256 + tid;          // 4096 float4 groups = 16x1024
    int row = idx >> 8, c = (idx & 255) * 4;
    float4 v = *(const float4*)(Ab + (size_t)row * NN + c);
    v4h hv;
    hv[0] = (_Float16)v.x; hv[1] = (_Float16)v.y;
    hv[2] = (_Float16)v.z; hv[3] = (_Float16)v.w;
    *(v4h*)(&Ah[row][c]) = hv;
  }
  __syncthreads();

  int w = tid >> 6, l = tid & 63;
  int kg = l >> 4, ln = l & 15;
  float si = sil[w][ln];
  int bh = b * HH + w;
  v4f acc[4] = {{}, {}, {}, {}};
  const _Float16* VTb = VTt + (size_t)bh * 32 * 64 * 32;
  const float* tj = tjl[w];

#define PEXP(av, tv) \
  ((float)(av) * __builtin_amdgcn_exp2f(fmaxf(si + (tv), SLOPE * (si + (tv)))))

#pragma unroll 2
  for (int jb = 0; jb < 32; ++jb) {
    int j = jb * 32 + kg * 8;
    v8h ar = *(const v8h*)(&Ah[ln][j]);
    float4 t0 = *(const float4*)(tj + j);
    float4 t1 = *(const float4*)(tj + j + 4);
    v8h af;
    af[0] = (_Float16)PEXP(ar[0], t0.x);
    af[1] = (_Float16)PEXP(ar[1], t0.y);
    af[2] = (_Float16)PEXP(ar[2], t0.z);
    af[3] = (_Float16)PEXP(ar[3], t0.w);
    af[4] = (_Float16)PEXP(ar[4], t1.x);
    af[5] = (_Float16)PEXP(ar[5], t1.y);
    af[6] = (_Float16)PEXP(ar[6], t1.z);
    af[7] = (_Float16)PEXP(ar[7], t1.w);
    const _Float16* vb = VTb + (size_t)jb * 2048 + kg * 8;
    v8h b0 = *(const v8h*)(vb + (0 * 16 + ln) * 32);
    v8h b1 = *(const v8h*)(vb + (1 * 16 + ln) * 32);
    v8h b2 = *(const v8h*)(vb + (2 * 16 + ln) * 32);
    v8h b3 = *(const v8h*)(vb + (3 * 16 + ln) * 32);
    acc[0] = __builtin_amdgcn_mfma_f32_16x16x32_f16(af, b0, acc[0], 0, 0, 0);
    acc[1] = __builtin_amdgcn_mfma_f32_16x16x32_f16(af, b1, acc[1], 0, 0, 0);
    acc[2] = __builtin_amdgcn_mfma_f32_16x16x32_f16(af, b2, acc[2], 0, 0, 0);
    acc[3] = __builtin_amdgcn_mfma_f32_16x16x32_f16(af, b3, acc[3], 0, 0, 0);
  }
#undef PEXP

  // D layout: col = ln (o = t*16+ln), row = kg*4 + r
#pragma unroll
  for (int r = 0; r < 4; ++r) {
    int gi = i0 + kg * 4 + r;
    float* op = out + ((size_t)b * NN + gi) * 256 + w * 64;
    op[0 * 16 + ln] = acc[0][r];
    op[1 * 16 + ln] = acc[1][r];
    op[2 * 16 + ln] = acc[2][r];
    op[3 * 16 + ln] = acc[3][r];
  }
}

extern "C" void kernel_launch(void* const* d_in, const int* in_sizes, int n_in,
                              void* d_out, int out_size, void* d_ws,
                              size_t ws_size, hipStream_t stream) {
  const float* A = (const float*)d_in[0];
  const float* x = (const float*)d_in[1];
  const float* W = (const float*)d_in[2];
  const float* aw = (const float*)d_in[3];
  const float* ab = (const float*)d_in[4];
  float* out = (float*)d_out;
  char* ws = (char*)d_ws;
  _Float16* WhH = (_Float16*)ws;                       // 4 MB: (B,H,N,64) f16
  _Float16* VTt = (_Float16*)(ws + (4u << 20));        // 4 MB: (B,H,32,64,32) f16 tiled
  _Float16* Wt = (_Float16*)(ws + (8u << 20));         // 64 KB: (256,128) f16
  float* si2 = (float*)(ws + (8u << 20) + (256u << 10));   // 128 KB
  float* tj2 = (float*)(ws + (8u << 20) + (384u << 10));   // 128 KB
  float* part = (float*)(ws + (8u << 20) + (512u << 10));  // 4 MB (32 splits)

  hipLaunchKernelGGL(k0_wt, dim3(32), dim3(256), 0, stream, W, Wt);
  hipLaunchKernelGGL(k1_whm, dim3(512), dim3(256), 0, stream, x, Wt, aw, ab,
                     WhH, si2, tj2);
  hipLaunchKernelGGL(k2_colsum, dim3(4, 32, BB), dim3(256), 0, stream, A, si2,
                     tj2, part);
  hipLaunchKernelGGL(k3_scale_tr, dim3(16, BB * HH), dim3(256), 0, stream, WhH,
                     part, VTt);
  hipLaunchKernelGGL(k4_pv, dim3(64, BB), dim3(256), 0, stream, A, si2, tj2,
                     VTt, out);
}

// Round 4
// 48.048 us; speedup vs baseline: 1.8572x; 1.1376x over previous
//
#include <hip/hip_runtime.h>
#include <hip/hip_bf16.h>
#include <hip/hip_fp16.h>

#define BB 8
#define NN 1024
#define FIN 128
#define FOUT 64
#define HH 4
#define EPSV 1e-7f
#define SLOPE 0.2f
#define LOG2E 1.44269504088896340736f

typedef _Float16 v8h __attribute__((ext_vector_type(8)));
typedef _Float16 v4h __attribute__((ext_vector_type(4)));
typedef float v4f __attribute__((ext_vector_type(4)));

// ---------------- K0: Wtt[ct][kgg][16][8]: (ct*16+ln, kgg*8+e) of Wt --------
// Wt[c][k] = W[h=c>>6][k][o=c&63]; 32768 elems, 8 blocks x 256 x 16
__global__ __launch_bounds__(256) void k0_wt(const float* __restrict__ W,
                                             _Float16* __restrict__ Wtt) {
  for (int it = 0; it < 16; ++it) {
    int idx = blockIdx.x * 4096 + it * 256 + threadIdx.x;
    int e = idx & 7, ln = (idx >> 3) & 15, kgg = (idx >> 7) & 15,
        ct = idx >> 11;
    int c = ct * 16 + ln, k = kgg * 8 + e;
    Wtt[idx] = (_Float16)W[(size_t)(c >> 6) * 8192 + k * 64 + (c & 63)];
  }
}

// ---------------- K1: Wh = x @ W via MFMA f16 + fused s_i/s_j ---------------
// grid 512 (16-row M-tiles over B*N=8192), block 256 = 4 waves (wave = head)
__global__ __launch_bounds__(256) void k1_whm(const float* __restrict__ x,
                                              const _Float16* __restrict__ Wtt,
                                              const float* __restrict__ aw,
                                              const float* __restrict__ ab,
                                              _Float16* __restrict__ WhH,
                                              float* __restrict__ si2,
                                              float* __restrict__ tj2) {
  __shared__ _Float16 xs[16][136];
  int tid = threadIdx.x;
  // stage x tile (16 x 128 f32) -> f16 LDS, coalesced
#pragma unroll
  for (int t2 = 0; t2 < 2; ++t2) {
    int idx = t2 * 256 + tid;            // 512 float4 groups
    int row = idx >> 5, c4 = (idx & 31) * 4;
    float4 v = *(const float4*)(x + ((size_t)blockIdx.x * 16 + row) * FIN + c4);
    v4h hv;
    hv[0] = (_Float16)v.x; hv[1] = (_Float16)v.y;
    hv[2] = (_Float16)v.z; hv[3] = (_Float16)v.w;
    *(v4h*)(&xs[row][c4]) = hv;
  }
  __syncthreads();
  int w = tid >> 6, l = tid & 63;
  int kg = l >> 4, ln = l & 15;
  v4f acc[4] = {{}, {}, {}, {}};
#pragma unroll
  for (int ks = 0; ks < 4; ++ks) {
    v8h af = *(const v8h*)(&xs[ln][ks * 32 + kg * 8]);
    int kgg = ks * 4 + kg;
#pragma unroll
    for (int t = 0; t < 4; ++t) {
      int ct = w * 4 + t;
      v8h bf = *(const v8h*)(Wtt + (((size_t)ct * 16 + kgg) * 16 + ln) * 8);
      acc[t] = __builtin_amdgcn_mfma_f32_16x16x32_f16(af, bf, acc[t], 0, 0, 0);
    }
  }
  float a1v[4], a2v[4];
#pragma unroll
  for (int t = 0; t < 4; ++t) {
    a1v[t] = aw[w * 128 + t * 16 + ln];
    a2v[t] = aw[w * 128 + 64 + t * 16 + ln];
  }
  float abv = ab[w];
#pragma unroll
  for (int r = 0; r < 4; ++r) {
    float v1 = acc[0][r] * a1v[0] + acc[1][r] * a1v[1] +
               acc[2][r] * a1v[2] + acc[3][r] * a1v[3];
    float v2 = acc[0][r] * a2v[0] + acc[1][r] * a2v[1] +
               acc[2][r] * a2v[2] + acc[3][r] * a2v[3];
#pragma unroll
    for (int off = 1; off < 16; off <<= 1) {
      v1 += __shfl_xor(v1, off);
      v2 += __shfl_xor(v2, off);
    }
    if (ln == 0) {
      int gr = blockIdx.x * 16 + kg * 4 + r;
      int b_ = gr >> 10, n_ = gr & 1023;
      size_t row = ((size_t)b_ * HH + w) * NN + n_;
      si2[row] = v1 * LOG2E;
      tj2[row] = (v2 + abv) * LOG2E;
    }
  }
#pragma unroll
  for (int t = 0; t < 4; ++t) {
#pragma unroll
    for (int r = 0; r < 4; ++r) {
      int gr = blockIdx.x * 16 + kg * 4 + r;
      int b_ = gr >> 10, n_ = gr & 1023;
      WhH[(((size_t)b_ * HH + w) * NN + n_) * 64 + (t * 16 + ln)] =
          (_Float16)acc[t][r];
    }
  }
}

// ---------------- K2: partial column sums of exps over i ---------------------
__global__ __launch_bounds__(256) void k2_colsum(const float* __restrict__ A,
                                                 const float* __restrict__ si2,
                                                 const float* __restrict__ tj2,
                                                 float* __restrict__ part) {
  __shared__ float sil[4][32];
  int b = blockIdx.z, is = blockIdx.y, jt = blockIdx.x;
  int tid = threadIdx.x;
  int j = jt * 256 + tid;
  int i0 = is * 32;
  if (tid < 128) {
    int h = tid >> 5, ii = tid & 31;
    sil[h][ii] = si2[((size_t)(b * HH + h)) * NN + i0 + ii];
  }
  __syncthreads();
  float tjv[4], acc[4] = {0.f, 0.f, 0.f, 0.f};
#pragma unroll
  for (int h = 0; h < 4; ++h) tjv[h] = tj2[((size_t)(b * HH + h)) * NN + j];
  const float* Ap = A + ((size_t)b * NN + i0) * NN + j;
#pragma unroll 4
  for (int ii = 0; ii < 32; ++ii) {
    float a = Ap[(size_t)ii * NN];
#pragma unroll
    for (int h = 0; h < 4; ++h) {
      float f = sil[h][ii] + tjv[h];
      float g = fmaxf(f, SLOPE * f);
      acc[h] += a * __builtin_amdgcn_exp2f(g);
    }
  }
#pragma unroll
  for (int h = 0; h < 4; ++h)
    part[((size_t)(is * 32) + b * HH + h) * NN + j] = acc[h];
}

// ---------------- K3: r[j]=1/(colsum+eps); VTt[bh][jb][o][jj] = (f16) r*Wh --
// 1D grid 512, XCD-swizzled: b = bid&7 so writes land in the L2 that reads them
__global__ __launch_bounds__(256) void k3_scale_tr(
    const _Float16* __restrict__ WhH, const float* __restrict__ part,
    _Float16* __restrict__ VTt) {
  __shared__ float rbuf[64];
  __shared__ _Float16 tile[64 * 66];
  int bid = blockIdx.x;
  int b = bid & 7, rest = bid >> 3;
  int h = rest & 3, jt = rest >> 2;
  int bh = b * HH + h, j0 = jt * 64;
  int tid = threadIdx.x;
  if (tid < 64) {
    float s = 0.f;
#pragma unroll
    for (int is = 0; is < 32; ++is)
      s += part[((size_t)(is * 32) + bh) * NN + j0 + tid];
    rbuf[tid] = 1.0f / (s + EPSV);
  }
  __syncthreads();
#pragma unroll
  for (int it = 0; it < 16; ++it) {
    int lin = it * 256 + tid;
    int jj = lin >> 6, o = lin & 63;
    float v = (float)WhH[((size_t)bh * NN + j0 + jj) * 64 + o] * rbuf[jj];
    tile[o * 66 + jj] = (_Float16)v;
  }
  __syncthreads();
#pragma unroll
  for (int it = 0; it < 16; ++it) {
    int lin = it * 256 + tid;
    int o = lin >> 6, jj64 = lin & 63;
    int j = j0 + jj64;
    int jb = j >> 5, jj = j & 31;
    VTt[(((size_t)bh * 32 + jb) * 64 + o) * 32 + jj] = tile[o * 66 + jj64];
  }
}

// ---------------- K4: out[i,:] = sum_j P[i,j] * V'[j,:] via MFMA ------------
// 1D grid 256, b = bid&7 (XCD-local VT), it = bid>>3. Block: 32 i-rows x 4
// heads (wave = head, 2 A-frags per wave). A f16 in LDS; VT reads coalesced.
__global__ __launch_bounds__(256) void k4_pv(const float* __restrict__ A,
                                             const float* __restrict__ si2,
                                             const float* __restrict__ tj2,
                                             const _Float16* __restrict__ VTt,
                                             float* __restrict__ out) {
  __shared__ _Float16 Ah[32][1032];
  __shared__ float tjl[4][1024];
  __shared__ float sil[4][32];
  int bid = blockIdx.x;
  int b = bid & 7, it = bid >> 3;
  int i0 = it * 32;
  int tid = threadIdx.x;
#pragma unroll
  for (int t2 = 0; t2 < 16; ++t2) {
    int idx = t2 * 256 + tid;
    int h = idx >> 10, j = idx & 1023;
    tjl[h][j] = tj2[((size_t)(b * HH + h)) * NN + j];
  }
  if (tid < 128) {
    int h = tid >> 5, ii = tid & 31;
    sil[h][ii] = si2[((size_t)(b * HH + h)) * NN + i0 + ii];
  }
  const float* Ab = A + ((size_t)b * NN + i0) * NN;
#pragma unroll 8
  for (int t2 = 0; t2 < 32; ++t2) {
    int idx = t2 * 256 + tid;          // 8192 float4 groups = 32x1024
    int row = idx >> 8, c = (idx & 255) * 4;
    float4 v = *(const float4*)(Ab + (size_t)row * NN + c);
    v4h hv;
    hv[0] = (_Float16)v.x; hv[1] = (_Float16)v.y;
    hv[2] = (_Float16)v.z; hv[3] = (_Float16)v.w;
    *(v4h*)(&Ah[row][c]) = hv;
  }
  __syncthreads();

  int w = tid >> 6, l = tid & 63;
  int kg = l >> 4, ln = l & 15;
  float si0 = sil[w][ln];
  float si1 = sil[w][16 + ln];
  int bh = b * HH + w;
  v4f acc0[4] = {{}, {}, {}, {}};
  v4f acc1[4] = {{}, {}, {}, {}};
  const _Float16* VTb = VTt + (size_t)bh * 32 * 64 * 32;
  const float* tj = tjl[w];

#define PEXP(si, av, tv) \
  ((float)(av) * \
   __builtin_amdgcn_exp2f(fmaxf((si) + (tv), SLOPE * ((si) + (tv)))))

#pragma unroll 2
  for (int jb = 0; jb < 32; ++jb) {
    int j = jb * 32 + kg * 8;
    v8h ar0 = *(const v8h*)(&Ah[ln][j]);
    v8h ar1 = *(const v8h*)(&Ah[16 + ln][j]);
    float4 t0 = *(const float4*)(tj + j);
    float4 t1 = *(const float4*)(tj + j + 4);
    v8h af0, af1;
    af0[0] = (_Float16)PEXP(si0, ar0[0], t0.x);
    af0[1] = (_Float16)PEXP(si0, ar0[1], t0.y);
    af0[2] = (_Float16)PEXP(si0, ar0[2], t0.z);
    af0[3] = (_Float16)PEXP(si0, ar0[3], t0.w);
    af0[4] = (_Float16)PEXP(si0, ar0[4], t1.x);
    af0[5] = (_Float16)PEXP(si0, ar0[5], t1.y);
    af0[6] = (_Float16)PEXP(si0, ar0[6], t1.z);
    af0[7] = (_Float16)PEXP(si0, ar0[7], t1.w);
    af1[0] = (_Float16)PEXP(si1, ar1[0], t0.x);
    af1[1] = (_Float16)PEXP(si1, ar1[1], t0.y);
    af1[2] = (_Float16)PEXP(si1, ar1[2], t0.z);
    af1[3] = (_Float16)PEXP(si1, ar1[3], t0.w);
    af1[4] = (_Float16)PEXP(si1, ar1[4], t1.x);
    af1[5] = (_Float16)PEXP(si1, ar1[5], t1.y);
    af1[6] = (_Float16)PEXP(si1, ar1[6], t1.z);
    af1[7] = (_Float16)PEXP(si1, ar1[7], t1.w);
    const _Float16* vb = VTb + (size_t)jb * 2048 + kg * 8;
    v8h b0 = *(const v8h*)(vb + (0 * 16 + ln) * 32);
    v8h b1 = *(const v8h*)(vb + (1 * 16 + ln) * 32);
    v8h b2 = *(const v8h*)(vb + (2 * 16 + ln) * 32);
    v8h b3 = *(const v8h*)(vb + (3 * 16 + ln) * 32);
    acc0[0] = __builtin_amdgcn_mfma_f32_16x16x32_f16(af0, b0, acc0[0], 0, 0, 0);
    acc1[0] = __builtin_amdgcn_mfma_f32_16x16x32_f16(af1, b0, acc1[0], 0, 0, 0);
    acc0[1] = __builtin_amdgcn_mfma_f32_16x16x32_f16(af0, b1, acc0[1], 0, 0, 0);
    acc1[1] = __builtin_amdgcn_mfma_f32_16x16x32_f16(af1, b1, acc1[1], 0, 0, 0);
    acc0[2] = __builtin_amdgcn_mfma_f32_16x16x32_f16(af0, b2, acc0[2], 0, 0, 0);
    acc1[2] = __builtin_amdgcn_mfma_f32_16x16x32_f16(af1, b2, acc1[2], 0, 0, 0);
    acc0[3] = __builtin_amdgcn_mfma_f32_16x16x32_f16(af0, b3, acc0[3], 0, 0, 0);
    acc1[3] = __builtin_amdgcn_mfma_f32_16x16x32_f16(af1, b3, acc1[3], 0, 0, 0);
  }
#undef PEXP

  // D layout: col = ln (o = t*16+ln), row = kg*4 + r
#pragma unroll
  for (int r = 0; r < 4; ++r) {
    int gi0 = i0 + kg * 4 + r;
    float* op0 = out + ((size_t)b * NN + gi0) * 256 + w * 64;
    op0[0 * 16 + ln] = acc0[0][r];
    op0[1 * 16 + ln] = acc0[1][r];
    op0[2 * 16 + ln] = acc0[2][r];
    op0[3 * 16 + ln] = acc0[3][r];
    float* op1 = op0 + 16 * 256;
    op1[0 * 16 + ln] = acc1[0][r];
    op1[1 * 16 + ln] = acc1[1][r];
    op1[2 * 16 + ln] = acc1[2][r];
    op1[3 * 16 + ln] = acc1[3][r];
  }
}

extern "C" void kernel_launch(void* const* d_in, const int* in_sizes, int n_in,
                              void* d_out, int out_size, void* d_ws,
                              size_t ws_size, hipStream_t stream) {
  const float* A = (const float*)d_in[0];
  const float* x = (const float*)d_in[1];
  const float* W = (const float*)d_in[2];
  const float* aw = (const float*)d_in[3];
  const float* ab = (const float*)d_in[4];
  float* out = (float*)d_out;
  char* ws = (char*)d_ws;
  _Float16* WhH = (_Float16*)ws;                       // 4 MB: (B,H,N,64) f16
  _Float16* VTt = (_Float16*)(ws + (4u << 20));        // 4 MB: (B,H,32,64,32) f16 tiled
  _Float16* Wtt = (_Float16*)(ws + (8u << 20));        // 64 KB tiled W
  float* si2 = (float*)(ws + (8u << 20) + (256u << 10));   // 128 KB
  float* tj2 = (float*)(ws + (8u << 20) + (384u << 10));   // 128 KB
  float* part = (float*)(ws + (8u << 20) + (512u << 10));  // 4 MB (32 splits)

  hipLaunchKernelGGL(k0_wt, dim3(8), dim3(256), 0, stream, W, Wtt);
  hipLaunchKernelGGL(k1_whm, dim3(512), dim3(256), 0, stream, x, Wtt, aw, ab,
                     WhH, si2, tj2);
  hipLaunchKernelGGL(k2_colsum, dim3(4, 32, BB), dim3(256), 0, stream, A, si2,
                     tj2, part);
  hipLaunchKernelGGL(k3_scale_tr, dim3(512), dim3(256), 0, stream, WhH, part,
                     VTt);
  hipLaunchKernelGGL(k4_pv, dim3(256), dim3(256), 0, stream, A, si2, tj2, VTt,
                     out);
}